// Round 1
// baseline (3628.423 us; speedup 1.0000x reference)
//
#include <hip/hip_runtime.h>
#include <hip/hip_bf16.h>

#define NROWS 8192
#define DDIM 4096
#define CDIM 32000
#define IGN (-100)

#define BM 128
#define BN 128
#define BK 32
#define NCHUNK 10
#define PANELS 25   // NCHUNK * PANELS * BN == CDIM

typedef float f32x4 __attribute__((ext_vector_type(4)));
typedef __bf16 bf16x8 __attribute__((ext_vector_type(8)));
typedef unsigned short us4 __attribute__((ext_vector_type(4)));

static_assert(NCHUNK * PANELS * BN == CDIM, "C tiling");
static_assert(NROWS % BM == 0, "M tiling");
static_assert(DDIM % BK == 0, "K tiling");

__device__ __forceinline__ unsigned short f2bf(float f) {
    unsigned int u = __float_as_uint(f);
    u += 0x7FFF + ((u >> 16) & 1);   // round-to-nearest-even
    return (unsigned short)(u >> 16);
}

// ---------------- fp32 -> bf16 conversion (vectorized) ----------------
__global__ void cvt_kernel(const float4* __restrict__ src, us4* __restrict__ dst, long n4) {
    long i = (long)blockIdx.x * blockDim.x + threadIdx.x;
    long st = (long)gridDim.x * blockDim.x;
    for (; i < n4; i += st) {
        float4 v = src[i];
        us4 o;
        o.x = f2bf(v.x); o.y = f2bf(v.y); o.z = f2bf(v.z); o.w = f2bf(v.w);
        dst[i] = o;
    }
}

// ---------------- fused GEMM + online logsumexp ----------------
// grid: (NROWS/BM, NCHUNK). Each block: BM rows x (PANELS*BN) classes.
// Writes per-row partial (max, sumexp) for its chunk.
__global__ __launch_bounds__(256, 2) void gemm_lse_kernel(
    const unsigned short* __restrict__ Xb,   // [NROWS][DDIM] bf16 bits
    const unsigned short* __restrict__ Lb,   // [CDIM][DDIM] bf16 bits
    float2* __restrict__ partials)           // [NCHUNK][NROWS]
{
    __shared__ __align__(16) unsigned short As[BM * BK];
    __shared__ __align__(16) unsigned short Bs[BN * BK];
    __shared__ float m_ws[2][BM];
    __shared__ float s_ws[2][BM];
    __shared__ float m_run[BM];
    __shared__ float l_run[BM];

    const int tid  = threadIdx.x;
    const int lane = tid & 63;
    const int w    = tid >> 6;      // wave 0..3
    const int wr   = w >> 1;        // wave row (0..1) -> 64 rows
    const int wc   = w & 1;         // wave col (0..1) -> 64 cols
    const int g    = lane >> 4;     // 0..3
    const int lr   = lane & 15;
    const int rowBase = blockIdx.x * BM;
    const int chunk   = blockIdx.y;

    if (tid < BM) { m_run[tid] = -__builtin_inff(); l_run[tid] = 0.f; }

    // staging: 512 chunks of 16B per tile; chunk c -> row c>>2, k-group c&3
    const int crow = tid >> 2;            // 0..63
    const int ckg  = (tid & 3) * 8;       // element offset in K
    const unsigned short* aSrc0 = Xb + (size_t)(rowBase + crow) * DDIM + ckg;
    const unsigned short* aSrc1 = aSrc0 + (size_t)64 * DDIM;

    unsigned short* aDst0 = As + w * 512;
    unsigned short* aDst1 = As + 2048 + w * 512;
    unsigned short* bDst0 = Bs + w * 512;
    unsigned short* bDst1 = Bs + 2048 + w * 512;

    for (int p = 0; p < PANELS; ++p) {
        const int colBase = (chunk * PANELS + p) * BN;
        const unsigned short* bSrc0 = Lb + (size_t)(colBase + crow) * DDIM + ckg;
        const unsigned short* bSrc1 = bSrc0 + (size_t)64 * DDIM;

        f32x4 acc[4][4];
#pragma unroll
        for (int mi = 0; mi < 4; ++mi)
#pragma unroll
            for (int ni = 0; ni < 4; ++ni)
                acc[mi][ni] = (f32x4)(0.f);

        for (int k0 = 0; k0 < DDIM; k0 += BK) {
            __syncthreads();   // previous iter's ds_reads done before overwrite
            __builtin_amdgcn_global_load_lds(
                (const __attribute__((address_space(1))) void*)(aSrc0 + k0),
                (__attribute__((address_space(3))) void*)aDst0, 16, 0, 0);
            __builtin_amdgcn_global_load_lds(
                (const __attribute__((address_space(1))) void*)(aSrc1 + k0),
                (__attribute__((address_space(3))) void*)aDst1, 16, 0, 0);
            __builtin_amdgcn_global_load_lds(
                (const __attribute__((address_space(1))) void*)(bSrc0 + k0),
                (__attribute__((address_space(3))) void*)bDst0, 16, 0, 0);
            __builtin_amdgcn_global_load_lds(
                (const __attribute__((address_space(1))) void*)(bSrc1 + k0),
                (__attribute__((address_space(3))) void*)bDst1, 16, 0, 0);
            __syncthreads();   // staging complete (vmcnt(0) before barrier)

            bf16x8 af[4], bfv[4];
#pragma unroll
            for (int mi = 0; mi < 4; ++mi)
                af[mi] = *(const bf16x8*)&As[(wr * 64 + mi * 16 + lr) * BK + g * 8];
#pragma unroll
            for (int ni = 0; ni < 4; ++ni)
                bfv[ni] = *(const bf16x8*)&Bs[(wc * 64 + ni * 16 + lr) * BK + g * 8];
#pragma unroll
            for (int mi = 0; mi < 4; ++mi)
#pragma unroll
                for (int ni = 0; ni < 4; ++ni)
                    acc[mi][ni] = __builtin_amdgcn_mfma_f32_16x16x32_bf16(
                        af[mi], bfv[ni], acc[mi][ni], 0, 0, 0);
        }

        // ---- per-panel online LSE update ----
        // lane holds: rows (mi*16 + g*4 + r), col (ni*16 + lr) within wave tile
        float rmax[4][4], rsum[4][4];
#pragma unroll
        for (int mi = 0; mi < 4; ++mi)
#pragma unroll
            for (int r = 0; r < 4; ++r) {
                float m = acc[mi][0][r];
                m = fmaxf(m, acc[mi][1][r]);
                m = fmaxf(m, acc[mi][2][r]);
                m = fmaxf(m, acc[mi][3][r]);
                rmax[mi][r] = m;
            }
#pragma unroll
        for (int d = 1; d < 16; d <<= 1)
#pragma unroll
            for (int mi = 0; mi < 4; ++mi)
#pragma unroll
                for (int r = 0; r < 4; ++r)
                    rmax[mi][r] = fmaxf(rmax[mi][r], __shfl_xor(rmax[mi][r], d, 64));
#pragma unroll
        for (int mi = 0; mi < 4; ++mi)
#pragma unroll
            for (int r = 0; r < 4; ++r) {
                float mm = rmax[mi][r];
                rsum[mi][r] = __expf(acc[mi][0][r] - mm) + __expf(acc[mi][1][r] - mm)
                            + __expf(acc[mi][2][r] - mm) + __expf(acc[mi][3][r] - mm);
            }
#pragma unroll
        for (int d = 1; d < 16; d <<= 1)
#pragma unroll
            for (int mi = 0; mi < 4; ++mi)
#pragma unroll
                for (int r = 0; r < 4; ++r)
                    rsum[mi][r] += __shfl_xor(rsum[mi][r], d, 64);

        if (lr == 0) {
#pragma unroll
            for (int mi = 0; mi < 4; ++mi)
#pragma unroll
                for (int r = 0; r < 4; ++r) {
                    int rl = wr * 64 + mi * 16 + g * 4 + r;
                    m_ws[wc][rl] = rmax[mi][r];
                    s_ws[wc][rl] = rsum[mi][r];
                }
        }
        __syncthreads();
        if (tid < BM) {
            float m0 = m_ws[0][tid], s0 = s_ws[0][tid];
            float m1 = m_ws[1][tid], s1 = s_ws[1][tid];
            float mo = m_run[tid],  lo = l_run[tid];
            float M = fmaxf(fmaxf(m0, m1), mo);
            float l = lo * __expf(mo - M) + s0 * __expf(m0 - M) + s1 * __expf(m1 - M);
            m_run[tid] = M;
            l_run[tid] = l;
        }
        __syncthreads();
    }

    if (tid < BM) {
        partials[(size_t)chunk * NROWS + rowBase + tid] =
            make_float2(m_run[tid], l_run[tid]);
    }
}

// ---------------- target logit: exact fp32 dot per row ----------------
__global__ void tgt_dot_kernel(const float* __restrict__ x, const float* __restrict__ L,
                               const int* __restrict__ tgt, float* __restrict__ out) {
    int row = blockIdx.x * 4 + (threadIdx.x >> 6);
    int lane = threadIdx.x & 63;
    if (row >= NROWS) return;
    int t = tgt[row];
    float sum = 0.f;
    if (t != IGN) {
        const float4* xr = (const float4*)(x + (size_t)row * DDIM);
        const float4* lr = (const float4*)(L + (size_t)t * DDIM);
        for (int i = lane; i < DDIM / 4; i += 64) {
            float4 a = xr[i], b = lr[i];
            sum += a.x * b.x + a.y * b.y + a.z * b.z + a.w * b.w;
        }
    }
#pragma unroll
    for (int d = 32; d; d >>= 1) sum += __shfl_xor(sum, d, 64);
    if (lane == 0) out[row] = sum;
}

// ---------------- combine partials + mean-reduce to scalar ----------------
__global__ void finalize_kernel(const float2* __restrict__ partials,
                                const float* __restrict__ tgtlog,
                                const int* __restrict__ tgt,
                                float* __restrict__ out) {
    __shared__ float ssum[256];
    __shared__ float scnt[256];
    int tid = threadIdx.x;
    float lsum = 0.f, lcnt = 0.f;
    for (int row = tid; row < NROWS; row += 256) {
        int t = tgt[row];
        if (t == IGN) continue;
        float M = -__builtin_inff();
        float2 pp[NCHUNK];
#pragma unroll
        for (int c = 0; c < NCHUNK; ++c) {
            pp[c] = partials[(size_t)c * NROWS + row];
            M = fmaxf(M, pp[c].x);
        }
        float S = 0.f;
#pragma unroll
        for (int c = 0; c < NCHUNK; ++c)
            S += pp[c].y * __expf(pp[c].x - M);
        float logZ = M + logf(S);
        lsum += logZ - tgtlog[row];
        lcnt += 1.f;
    }
    ssum[tid] = lsum;
    scnt[tid] = lcnt;
    __syncthreads();
    for (int s = 128; s; s >>= 1) {
        if (tid < s) { ssum[tid] += ssum[tid + s]; scnt[tid] += scnt[tid + s]; }
        __syncthreads();
    }
    if (tid == 0) out[0] = ssum[0] / fmaxf(scnt[0], 1.f);
}

extern "C" void kernel_launch(void* const* d_in, const int* in_sizes, int n_in,
                              void* d_out, int out_size, void* d_ws, size_t ws_size,
                              hipStream_t stream) {
    const float* x   = (const float*)d_in[0];
    const int*   tgt = (const int*)d_in[1];
    const float* L   = (const float*)d_in[2];
    float* out = (float*)d_out;

    // workspace layout
    unsigned short* Xb = (unsigned short*)d_ws;                 // NROWS*DDIM bf16
    unsigned short* Lb = Xb + (size_t)NROWS * DDIM;             // CDIM*DDIM bf16
    float2* partials   = (float2*)(Lb + (size_t)CDIM * DDIM);   // NCHUNK*NROWS
    float*  tgtlog     = (float*)(partials + (size_t)NCHUNK * NROWS); // NROWS

    cvt_kernel<<<2048, 256, 0, stream>>>((const float4*)x, (us4*)Xb,
                                         (long)NROWS * DDIM / 4);
    cvt_kernel<<<2048, 256, 0, stream>>>((const float4*)L, (us4*)Lb,
                                         (long)CDIM * DDIM / 4);
    gemm_lse_kernel<<<dim3(NROWS / BM, NCHUNK), 256, 0, stream>>>(Xb, Lb, partials);
    tgt_dot_kernel<<<NROWS / 4, 256, 0, stream>>>(x, L, tgt, tgtlog);
    finalize_kernel<<<1, 256, 0, stream>>>(partials, tgtlog, tgt, out);
}